// Round 8
// baseline (333.997 us; speedup 1.0000x reference)
//
#include <hip/hip_runtime.h>
#include <math.h>

// CentroidInstanceLoss: N=2M points, D=16, B=8 subbatches, M=32 labels.
// out = (L_pull + L_push)/B  (single fp32 scalar)
//
// R8: branch-free hot loops + manual depth-4 rotating load pipeline.
// R2-R7 lesson: every variant with a data-dependent branch / LDS atomic in
// the hot loop pins at ~1 TB/s with VALUBusy <2% and VGPR<=48 -- the compiler
// keeps ONE load-group in flight per wave. Here the loop assumes per-thread
// seg invariance (verified branchlessly); any violation -> whole-block slow
// path re-run (correct for arbitrary inputs, never taken for canonical).

#define DD 16
#define MM 32
#define BBATCH 8
#define SEGS 256          // B*M
#define DELTA_V 0.5f
#define DELTA_D 1.5f
#define NEPS 1e-8f

#define NBLK 1024
#define NTHR 256
#define CHUNKP 2048               // points per block (NBLK*CHUNKP == N)
#define ITERS (CHUNKP * 4 / NTHR) // 32 float4-iterations per thread
#define PIPE 4                    // software-pipeline depth

// ws layout (floats):
//   [0,4096)        seg_sum   [seg][d]    (HW fp atomics)
//   [4096,4352)     seg_cnt   [seg]
//   [4352,8448)     mus       [seg][d]  (seg-major)
//   [8448,8704)     invw      [seg]   = 1/(M*count)
//   [8704]          push_acc
//   [8720,8720+NBLK) pull_part
#define WS_ZERO_FLOATS 4352

__device__ __forceinline__ void lds_fadd(float* p, float v) {
    __hip_atomic_fetch_add(p, v, __ATOMIC_RELAXED, __HIP_MEMORY_SCOPE_WORKGROUP);
}

__device__ __forceinline__ float block_reduce_sum(float v) {
    #pragma unroll
    for (int o = 32; o > 0; o >>= 1) v += __shfl_down(v, o, 64);
    __shared__ float red[4];
    int wid  = threadIdx.x >> 6;
    int lane = threadIdx.x & 63;
    if (lane == 0) red[wid] = v;
    __syncthreads();
    v = (threadIdx.x < (NTHR >> 6)) ? red[threadIdx.x] : 0.0f;
    if (wid == 0) {
        #pragma unroll
        for (int o = 32; o > 0; o >>= 1) v += __shfl_down(v, o, 64);
    }
    return v;  // valid on thread 0
}

__global__ void __launch_bounds__(NTHR, 4)
k_segsum(const float4* __restrict__ o4,
         const int* __restrict__ labels,
         const int* __restrict__ sub,
         float* __restrict__ seg_sum,
         float* __restrict__ seg_cnt,
         int n) {
    __shared__ float lsT[(DD + 1) * SEGS];  // planes [d][seg]; plane 16 = count
    __shared__ int bad;
    for (int i = threadIdx.x; i < (DD + 1) * SEGS; i += NTHR) lsT[i] = 0.0f;
    if (threadIdx.x == 0) bad = 0;
    __syncthreads();

    const int tid = threadIdx.x;
    const int j   = tid & 3;                 // quad slot, loop-invariant
    const int n4  = 4 * n;
    const int qbase = blockIdx.x * (CHUNKP * 4) + tid;

    // per-thread reference segment (first point, clamped)
    int qc0 = (qbase < n4) ? qbase : j;
    int p0  = qc0 >> 2;
    const int seg0 = sub[p0] * MM + labels[p0];

    // ---- fast path: branch-free, depth-4 pipelined ----
    float4 vb[PIPE]; int sb[PIPE], lb[PIPE];
    #pragma unroll
    for (int k = 0; k < PIPE; ++k) {
        int q  = qbase + k * NTHR;
        int qc = (q < n4) ? q : j;
        vb[k] = o4[qc];
        int p = qc >> 2;
        sb[k] = sub[p];
        lb[k] = labels[p];
    }

    float4 av = {0.0f, 0.0f, 0.0f, 0.0f};
    float cnt = 0.0f;
    int allok = 1;
    #pragma unroll 4
    for (int it = 0; it < ITERS; ++it) {
        int k = it & (PIPE - 1);
        float4 v = vb[k];
        int seg  = sb[k] * MM + lb[k];
        // refill slot with iteration it+PIPE (consumed 4 iterations later)
        {
            int qn  = qbase + (it + PIPE) * NTHR;
            int qcn = (qn < n4 && (it + PIPE) < ITERS) ? qn : j;
            vb[k] = o4[qcn];
            int pn = qcn >> 2;
            sb[k] = sub[pn];
            lb[k] = labels[pn];
        }
        int q = qbase + it * NTHR;
        int ok = (q < n4);
        float ss = v.x*v.x + v.y*v.y + v.z*v.z + v.w*v.w;
        ss += __shfl_xor(ss, 1, 64);
        ss += __shfl_xor(ss, 2, 64);
        float rn = 1.0f / (sqrtf(ss) + NEPS);
        float mk = ok ? 1.0f : 0.0f;
        rn *= mk;
        allok &= (!ok) | (seg == seg0);
        av.x += v.x * rn; av.y += v.y * rn;
        av.z += v.z * rn; av.w += v.w * rn;
        cnt += mk;
    }

    if (!allok) bad = 1;
    __syncthreads();

    if (bad == 0) {
        // flush registers once per thread
        lds_fadd(&lsT[(4*j + 0) * SEGS + seg0], av.x);
        lds_fadd(&lsT[(4*j + 1) * SEGS + seg0], av.y);
        lds_fadd(&lsT[(4*j + 2) * SEGS + seg0], av.z);
        lds_fadd(&lsT[(4*j + 3) * SEGS + seg0], av.w);
        if (j == 0) lds_fadd(&lsT[DD * SEGS + seg0], cnt);
    } else {
        // ---- slow path (arbitrary inputs): per-point streak flush (R7) ----
        float4 av2 = {0.0f, 0.0f, 0.0f, 0.0f};
        float cnt2 = 0.0f;
        int cur = -1;
        for (int it = 0; it < ITERS; ++it) {
            int q = qbase + it * NTHR;
            bool ok = (q < n4);
            int qc = ok ? q : j;
            float4 v = o4[qc];
            int p = qc >> 2;
            int seg = sub[p] * MM + labels[p];
            float ss = v.x*v.x + v.y*v.y + v.z*v.z + v.w*v.w;
            ss += __shfl_xor(ss, 1, 64);
            ss += __shfl_xor(ss, 2, 64);
            float rn = 1.0f / (sqrtf(ss) + NEPS);
            if (ok) {
                if (seg != cur) {
                    if (cur >= 0) {
                        lds_fadd(&lsT[(4*j + 0) * SEGS + cur], av2.x);
                        lds_fadd(&lsT[(4*j + 1) * SEGS + cur], av2.y);
                        lds_fadd(&lsT[(4*j + 2) * SEGS + cur], av2.z);
                        lds_fadd(&lsT[(4*j + 3) * SEGS + cur], av2.w);
                        if (j == 0) lds_fadd(&lsT[DD * SEGS + cur], cnt2);
                        av2 = (float4){0.0f, 0.0f, 0.0f, 0.0f};
                        cnt2 = 0.0f;
                    }
                    cur = seg;
                }
                av2.x += v.x * rn; av2.y += v.y * rn;
                av2.z += v.z * rn; av2.w += v.w * rn;
                cnt2 += 1.0f;
            }
        }
        if (cur >= 0) {
            lds_fadd(&lsT[(4*j + 0) * SEGS + cur], av2.x);
            lds_fadd(&lsT[(4*j + 1) * SEGS + cur], av2.y);
            lds_fadd(&lsT[(4*j + 2) * SEGS + cur], av2.z);
            lds_fadd(&lsT[(4*j + 3) * SEGS + cur], av2.w);
            if (j == 0) lds_fadd(&lsT[DD * SEGS + cur], cnt2);
        }
    }
    __syncthreads();
    // global flush: only segments this block actually touched
    for (int s = threadIdx.x; s < SEGS; s += NTHR) {
        float c = lsT[DD * SEGS + s];
        if (c != 0.0f) {
            #pragma unroll
            for (int d = 0; d < DD; ++d)
                unsafeAtomicAdd(&seg_sum[s * DD + d], lsT[d * SEGS + s]);
            unsafeAtomicAdd(&seg_cnt[s], c);
        }
    }
}

__global__ void k_finalize_push(float* __restrict__ ws) {
    const float* seg_sum = ws;
    const float* seg_cnt = ws + 4096;
    float* mus  = ws + 4352;
    float* invw = ws + 8448;
    float* push = ws + 8704;

    __shared__ float muT[DD * SEGS];
    int t = threadIdx.x;  // one seg per thread
    float cnt = seg_cnt[t];
    float ic  = (cnt > 0.0f) ? 1.0f / cnt : 0.0f;
    #pragma unroll
    for (int d = 0; d < DD; ++d) {
        float m = seg_sum[t * DD + d] * ic;
        mus[t * DD + d]   = m;
        muT[d * SEGS + t] = m;
    }
    invw[t] = (cnt > 0.0f) ? 1.0f / ((float)MM * cnt) : 0.0f;
    __syncthreads();

    int b = t >> 5, m1 = t & 31;
    float acc = 0.0f;
    for (int m2 = 0; m2 < MM; ++m2) {
        float pd = 0.0f;
        #pragma unroll
        for (int d = 0; d < DD; ++d)
            pd += fabsf(muT[d * SEGS + b * MM + m1] - muT[d * SEGS + b * MM + m2]);
        float h = 2.0f * DELTA_D - pd;
        if (m2 != m1 && h > 0.0f) acc += h * h;
    }
    float tot = block_reduce_sum(acc);
    if (t == 0) push[0] = tot / (float)(MM * (MM - 1));
}

__global__ void __launch_bounds__(NTHR, 4)
k_pull(const float4* __restrict__ o4,
       const int* __restrict__ labels,
       const int* __restrict__ sub,
       const float* __restrict__ mus,
       const float* __restrict__ invw,
       float* __restrict__ pull_part,
       int n) {
    __shared__ float muL[DD * SEGS];  // seg-major (matches ws mus layout)
    __shared__ float siw[SEGS];
    __shared__ int bad;
    for (int i = threadIdx.x; i < DD * SEGS; i += NTHR) muL[i] = mus[i];
    for (int i = threadIdx.x; i < SEGS; i += NTHR) siw[i] = invw[i];
    if (threadIdx.x == 0) bad = 0;
    __syncthreads();

    const int tid = threadIdx.x;
    const int j   = tid & 3;
    const int n4  = 4 * n;
    const int qbase = blockIdx.x * (CHUNKP * 4) + tid;

    int qc0 = (qbase < n4) ? qbase : j;
    int p0  = qc0 >> 2;
    const int seg0 = sub[p0] * MM + labels[p0];
    const float4 mreg = *(const float4*)&muL[seg0 * DD + 4 * j];
    const float iw0 = siw[seg0] * ((j == 0) ? 1.0f : 0.0f);

    float4 vb[PIPE]; int sb[PIPE], lb[PIPE];
    #pragma unroll
    for (int k = 0; k < PIPE; ++k) {
        int q  = qbase + k * NTHR;
        int qc = (q < n4) ? q : j;
        vb[k] = o4[qc];
        int p = qc >> 2;
        sb[k] = sub[p];
        lb[k] = labels[p];
    }

    float accF = 0.0f;
    int allok = 1;
    #pragma unroll 4
    for (int it = 0; it < ITERS; ++it) {
        int k = it & (PIPE - 1);
        float4 v = vb[k];
        int seg  = sb[k] * MM + lb[k];
        {
            int qn  = qbase + (it + PIPE) * NTHR;
            int qcn = (qn < n4 && (it + PIPE) < ITERS) ? qn : j;
            vb[k] = o4[qcn];
            int pn = qcn >> 2;
            sb[k] = sub[pn];
            lb[k] = labels[pn];
        }
        int q = qbase + it * NTHR;
        int ok = (q < n4);
        float ss = v.x*v.x + v.y*v.y + v.z*v.z + v.w*v.w;
        ss += __shfl_xor(ss, 1, 64);
        ss += __shfl_xor(ss, 2, 64);
        float rn = 1.0f / (sqrtf(ss) + NEPS);
        allok &= (!ok) | (seg == seg0);
        float d4 = fabsf(mreg.x - v.x * rn) + fabsf(mreg.y - v.y * rn)
                 + fabsf(mreg.z - v.z * rn) + fabsf(mreg.w - v.w * rn);
        d4 += __shfl_xor(d4, 1, 64);
        d4 += __shfl_xor(d4, 2, 64);
        float h  = fmaxf(d4 - DELTA_V, 0.0f);
        float mk = ok ? 1.0f : 0.0f;
        accF = fmaf(h * h * mk, iw0, accF);
    }

    if (!allok) bad = 1;
    __syncthreads();

    float acc = accF;
    if (bad != 0) {
        // slow path: per-point LDS centroid lookup (arbitrary inputs)
        acc = 0.0f;
        for (int it = 0; it < ITERS; ++it) {
            int q = qbase + it * NTHR;
            bool ok = (q < n4);
            int qc = ok ? q : j;
            float4 v = o4[qc];
            int p = qc >> 2;
            int seg = sub[p] * MM + labels[p];
            float ss = v.x*v.x + v.y*v.y + v.z*v.z + v.w*v.w;
            ss += __shfl_xor(ss, 1, 64);
            ss += __shfl_xor(ss, 2, 64);
            float rn = 1.0f / (sqrtf(ss) + NEPS);
            const float4 m = *(const float4*)&muL[seg * DD + 4 * j];
            float d4 = fabsf(m.x - v.x * rn) + fabsf(m.y - v.y * rn)
                     + fabsf(m.z - v.z * rn) + fabsf(m.w - v.w * rn);
            d4 += __shfl_xor(d4, 1, 64);
            d4 += __shfl_xor(d4, 2, 64);
            if (ok && j == 0) {
                float h = d4 - DELTA_V;
                if (h > 0.0f) acc = fmaf(h * h, siw[seg], acc);
            }
        }
    }
    float tot = block_reduce_sum(acc);
    if (threadIdx.x == 0) pull_part[blockIdx.x] = tot;
}

__global__ void k_final(const float* __restrict__ ws, float* __restrict__ out) {
    const float* push      = ws + 8704;
    const float* pull_part = ws + 8720;
    int t = threadIdx.x;
    float v = 0.0f;
    #pragma unroll
    for (int k = 0; k < NBLK / NTHR; ++k) v += pull_part[t + k * NTHR];
    float tot = block_reduce_sum(v);
    if (t == 0) out[0] = (tot + push[0]) * (1.0f / (float)BBATCH);
}

extern "C" void kernel_launch(void* const* d_in, const int* in_sizes, int n_in,
                              void* d_out, int out_size, void* d_ws, size_t ws_size,
                              hipStream_t stream) {
    const float* outputs = (const float*)d_in[0];
    const int* labels    = (const int*)d_in[1];
    const int* sub       = (const int*)d_in[2];
    int n = in_sizes[0] / DD;

    float* ws        = (float*)d_ws;
    float* seg_sum   = ws;
    float* seg_cnt   = ws + 4096;
    float* mus       = ws + 4352;
    float* invw      = ws + 8448;
    float* pull_part = ws + 8720;

    hipMemsetAsync(d_ws, 0, WS_ZERO_FLOATS * sizeof(float), stream);

    k_segsum<<<NBLK, NTHR, 0, stream>>>((const float4*)outputs, labels, sub,
                                        seg_sum, seg_cnt, n);
    k_finalize_push<<<1, NTHR, 0, stream>>>(ws);
    k_pull<<<NBLK, NTHR, 0, stream>>>((const float4*)outputs, labels, sub,
                                      mus, invw, pull_part, n);
    k_final<<<1, NTHR, 0, stream>>>(ws, (float*)d_out);
}